// Round 2
// baseline (298.826 us; speedup 1.0000x reference)
//
#include <hip/hip_runtime.h>
#include <hip/hip_bf16.h>
#include <stdint.h>

typedef unsigned short u16;
typedef __attribute__((ext_vector_type(8))) short bf16x8;
typedef __attribute__((ext_vector_type(4))) float f32x4;

#define SEQ    4096
#define EMB    512
#define HEADS  8
#define HDIM   64
#define NBATCH 2

__device__ __forceinline__ u16 f2bf(float f) {
  unsigned u = __builtin_bit_cast(unsigned, f);
  u += 0x7fffu + ((u >> 16) & 1u);
  return (u16)(u >> 16);
}

__device__ __forceinline__ void gld_lds16(const void* g, void* lds) {
  __builtin_amdgcn_global_load_lds(
      (const __attribute__((address_space(1))) unsigned int*)(uintptr_t)g,
      (__attribute__((address_space(3))) unsigned int*)(uint32_t)(uintptr_t)lds,
      16, 0, 0);
}

__device__ __forceinline__ float rmax16(float v) {
#pragma unroll
  for (int off = 1; off < 16; off <<= 1) v = fmaxf(v, __shfl_xor(v, off));
  return v;
}
__device__ __forceinline__ float rsum16(float v) {
#pragma unroll
  for (int off = 1; off < 16; off <<= 1) v += __shfl_xor(v, off);
  return v;
}

// ---- shared 128x128 GEMM mainloop: C = X[m0:,512] * W[n0:,512]^T (both K-contig)
// X is bf16 (via global_load_lds) when XBF16, else f32 converted in registers.
// W is always f32, converted in registers.
template <bool XBF16>
__device__ __forceinline__ void gemm512_tile(const void* __restrict__ Xv,
                                             const float* __restrict__ W,
                                             u16* lA, u16* lB,
                                             int m0, int n0,
                                             f32x4 acc[4][4]) {
  const int tid  = threadIdx.x;
  const int lane = tid & 63;
  const int wid  = tid >> 6;
  const int wr   = wid >> 1, wc = wid & 1;

  for (int k0 = 0; k0 < EMB; k0 += 32) {
    __syncthreads();
    if constexpr (XBF16) {
      const u16* X = (const u16*)Xv;
      const int srow = lane >> 2;        // row within 16-row issue
      const int soff = (lane & 3) * 8;   // 16B chunk within 32-elem row
#pragma unroll
      for (int i = 0; i < 2; ++i) {
        int rbase = wid * 32 + i * 16;
        gld_lds16(X + (size_t)(m0 + rbase + srow) * EMB + k0 + soff, lA + rbase * 32);
      }
    } else {
      const float* X = (const float*)Xv;
#pragma unroll
      for (int i = 0; i < 4; ++i) {
        int chunk = i * 256 + tid;       // 0..1023
        int row = chunk >> 3;            // 0..127
        int c4  = (chunk & 7) * 4;
        float4 v = *(const float4*)(X + (size_t)(m0 + row) * EMB + k0 + c4);
        ushort4 b;
        b.x = f2bf(v.x); b.y = f2bf(v.y); b.z = f2bf(v.z); b.w = f2bf(v.w);
        *(ushort4*)(lA + row * 32 + c4) = b;
      }
    }
#pragma unroll
    for (int i = 0; i < 4; ++i) {
      int chunk = i * 256 + tid;
      int row = chunk >> 3;
      int c4  = (chunk & 7) * 4;
      float4 v = *(const float4*)(W + (size_t)(n0 + row) * EMB + k0 + c4);
      ushort4 b;
      b.x = f2bf(v.x); b.y = f2bf(v.y); b.z = f2bf(v.z); b.w = f2bf(v.w);
      *(ushort4*)(lB + row * 32 + c4) = b;
    }
    __syncthreads();

    bf16x8 a[4], b[4];
#pragma unroll
    for (int t = 0; t < 4; ++t) {
      a[t] = *(const bf16x8*)(lA + (wr * 64 + t * 16 + (lane & 15)) * 32 + (lane >> 4) * 8);
      b[t] = *(const bf16x8*)(lB + (wc * 64 + t * 16 + (lane & 15)) * 32 + (lane >> 4) * 8);
    }
#pragma unroll
    for (int mr = 0; mr < 4; ++mr)
#pragma unroll
      for (int nc = 0; nc < 4; ++nc)
        acc[mr][nc] = __builtin_amdgcn_mfma_f32_16x16x32_bf16(a[mr], b[nc], acc[mr][nc], 0, 0, 0);
  }
}

// ---- QKV projections: grid (64, 4, 3), f32 in, bf16 out scattered to [n][h][s][d]; Q pre-scaled
__global__ __launch_bounds__(256, 2) void k_proj_qkv(
    const float* __restrict__ xq, const float* __restrict__ xk, const float* __restrict__ xv,
    const float* __restrict__ wq, const float* __restrict__ wk, const float* __restrict__ wv,
    u16* __restrict__ yq, u16* __restrict__ yk, u16* __restrict__ yv) {
  __shared__ u16 lA[128 * 32];
  __shared__ u16 lB[128 * 32];
  const int z = blockIdx.z;
  const float* X = (z == 0) ? xq : (z == 1) ? xk : xv;
  const float* W = (z == 0) ? wq : (z == 1) ? wk : wv;
  u16* Y         = (z == 0) ? yq : (z == 1) ? yk : yv;
  const float oscale = (z == 0) ? 0.04419417382f : 1.0f;  // 1/sqrt(512) folded into Q
  const int m0 = blockIdx.x * 128, n0 = blockIdx.y * 128;

  f32x4 acc[4][4] = {};
  gemm512_tile<false>(X, W, lA, lB, m0, n0, acc);

  const int lane = threadIdx.x & 63, wid = threadIdx.x >> 6;
  const int wr = wid >> 1, wc = wid & 1;
#pragma unroll
  for (int mr = 0; mr < 4; ++mr)
#pragma unroll
    for (int nc = 0; nc < 4; ++nc)
#pragma unroll
      for (int j = 0; j < 4; ++j) {
        int m = m0 + wr * 64 + mr * 16 + (lane >> 4) * 4 + j;
        int c = n0 + wc * 64 + nc * 16 + (lane & 15);
        int n = m >> 12, s = m & (SEQ - 1);
        int h = c >> 6, d = c & 63;
        Y[(((size_t)(n * HEADS + h)) * SEQ + s) * HDIM + d] = f2bf(acc[mr][nc][j] * oscale);
      }
}

// ---- output projection: grid (64, 4), X bf16 (ws), W f32, out f32 [m][512]
__global__ __launch_bounds__(256, 2) void k_proj_out(
    const u16* __restrict__ X, const float* __restrict__ W, float* __restrict__ Y) {
  __shared__ u16 lA[128 * 32];
  __shared__ u16 lB[128 * 32];
  const int m0 = blockIdx.x * 128, n0 = blockIdx.y * 128;
  f32x4 acc[4][4] = {};
  gemm512_tile<true>(X, W, lA, lB, m0, n0, acc);

  const int lane = threadIdx.x & 63, wid = threadIdx.x >> 6;
  const int wr = wid >> 1, wc = wid & 1;
#pragma unroll
  for (int mr = 0; mr < 4; ++mr)
#pragma unroll
    for (int nc = 0; nc < 4; ++nc)
#pragma unroll
      for (int j = 0; j < 4; ++j) {
        int m = m0 + wr * 64 + mr * 16 + (lane >> 4) * 4 + j;
        int c = n0 + wc * 64 + nc * 16 + (lane & 15);
        Y[(size_t)m * EMB + c] = acc[mr][nc][j];
      }
}

// ---- flash attention: grid (32, 16); block = 4 waves x 32 q-rows; KVBLK = 64 (all bf16 ws)
__global__ __launch_bounds__(256, 2) void k_attn(
    const u16* __restrict__ Qg, const u16* __restrict__ Kg,
    const u16* __restrict__ Vg, u16* __restrict__ Og) {
  __shared__ u16 lK[64 * 64];        // [kv][d], elem col ^ ((kv&7)<<3)
  __shared__ u16 lV[64 * 64];        // [d][kv], elem col ^ ((((d>>3)^d)&7)<<3)
  __shared__ u16 lP[4][32 * 64];     // per-wave [qr][kv], col ^ ((qr&7)<<3)

  const int tid = threadIdx.x, lane = tid & 63, wid = tid >> 6;
  const int lo16 = lane & 15, hi16 = lane >> 4;
  const int nh = blockIdx.y;                       // n*8 + h
  const int q0 = blockIdx.x * 128 + wid * 32;      // this wave's 32 q rows

  const u16* Qh = Qg + (size_t)nh * SEQ * HDIM;
  const u16* Kh = Kg + (size_t)nh * SEQ * HDIM;
  const u16* Vh = Vg + (size_t)nh * SEQ * HDIM;

  // hoist Q fragments (already scaled by 1/sqrt(512))
  bf16x8 qf[2][2];
#pragma unroll
  for (int mr = 0; mr < 2; ++mr)
#pragma unroll
    for (int kk = 0; kk < 2; ++kk)
      qf[mr][kk] = *(const bf16x8*)&Qh[(size_t)(q0 + mr * 16 + lo16) * HDIM + kk * 32 + hi16 * 8];

  float mrow[2][4], lrow[2][4];
  f32x4 o[2][4];
#pragma unroll
  for (int mr = 0; mr < 2; ++mr) {
#pragma unroll
    for (int j = 0; j < 4; ++j) { mrow[mr][j] = -1e30f; lrow[mr][j] = 0.f; }
#pragma unroll
    for (int nc = 0; nc < 4; ++nc) o[mr][nc] = 0.f;
  }

  for (int kv0 = 0; kv0 < SEQ; kv0 += 64) {
    __syncthreads();
    // stage K via global_load_lds, pre-swizzled global source (lane>>3 = row&7)
#pragma unroll
    for (int i = 0; i < 2; ++i) {
      int isx = wid * 2 + i;
      int row = isx * 8 + (lane >> 3);
      int col = ((lane & 7) * 8) ^ ((row & 7) << 3);
      gld_lds16(Kh + (size_t)(kv0 + row) * HDIM + col, lK + isx * 512);
    }
    // stage V transposed (bank-conflict-free scalar writes via d-dependent swizzle)
#pragma unroll
    for (int i = 0; i < 2; ++i) {
      int c   = tid + i * 256;       // 0..511
      int row = c >> 3;              // kv
      int cb  = (c & 7) * 8;         // d base
      bf16x8 vv = *(const bf16x8*)&Vh[(size_t)(kv0 + row) * HDIM + cb];
#pragma unroll
      for (int j = 0; j < 8; ++j) {
        int d  = cb + j;
        int sw = (((d >> 3) ^ d) & 7) << 3;
        lV[d * 64 + (row ^ sw)] = (u16)vv[j];
      }
    }
    __syncthreads();

    // QK^T: s[mr][nc], rows q = hi16*4+j, cols kv = nc*16+lo16
    f32x4 s[2][4] = {};
#pragma unroll
    for (int nc = 0; nc < 4; ++nc) {
      int kvc = nc * 16 + lo16;
      int swz = (kvc & 7) << 3;
#pragma unroll
      for (int kk = 0; kk < 2; ++kk) {
        bf16x8 kf = *(const bf16x8*)&lK[kvc * 64 + ((kk * 32 + hi16 * 8) ^ swz)];
#pragma unroll
        for (int mr = 0; mr < 2; ++mr)
          s[mr][nc] = __builtin_amdgcn_mfma_f32_16x16x32_bf16(qf[mr][kk], kf, s[mr][nc], 0, 0, 0);
      }
    }

    // online softmax (state replicated across the 16 lanes of each hi16 group)
#pragma unroll
    for (int mr = 0; mr < 2; ++mr)
#pragma unroll
      for (int j = 0; j < 4; ++j) {
        float mx = fmaxf(fmaxf(s[mr][0][j], s[mr][1][j]), fmaxf(s[mr][2][j], s[mr][3][j]));
        mx = rmax16(mx);
        float mn = fmaxf(mrow[mr][j], mx);
        float al = __expf(mrow[mr][j] - mn);
        mrow[mr][j] = mn;
        float rs = 0.f;
#pragma unroll
        for (int nc = 0; nc < 4; ++nc) {
          float p = __expf(s[mr][nc][j] - mn);
          s[mr][nc][j] = p;
          rs += p;
        }
        rs = rsum16(rs);
        lrow[mr][j] = lrow[mr][j] * al + rs;
#pragma unroll
        for (int nc = 0; nc < 4; ++nc) o[mr][nc][j] *= al;
      }

    // P -> per-wave LDS (C-frag layout -> A-frag layout)
#pragma unroll
    for (int mr = 0; mr < 2; ++mr)
#pragma unroll
      for (int nc = 0; nc < 4; ++nc)
#pragma unroll
        for (int j = 0; j < 4; ++j) {
          int prow = mr * 16 + hi16 * 4 + j;
          int pcol = nc * 16 + lo16;
          lP[wid][prow * 64 + (pcol ^ ((prow & 7) << 3))] = f2bf(s[mr][nc][j]);
        }

    // PV: o[mr][nc] += P[32][64] * V[64][64]
    bf16x8 pa[2][2];
#pragma unroll
    for (int mr = 0; mr < 2; ++mr)
#pragma unroll
      for (int kk = 0; kk < 2; ++kk) {
        int prow = mr * 16 + lo16;
        pa[mr][kk] = *(const bf16x8*)&lP[wid][prow * 64 + ((kk * 32 + hi16 * 8) ^ ((prow & 7) << 3))];
      }
#pragma unroll
    for (int nc = 0; nc < 4; ++nc) {
      int d  = nc * 16 + lo16;
      int sw = (((d >> 3) ^ d) & 7) << 3;
#pragma unroll
      for (int kk = 0; kk < 2; ++kk) {
        bf16x8 vf = *(const bf16x8*)&lV[d * 64 + ((kk * 32 + hi16 * 8) ^ sw)];
#pragma unroll
        for (int mr = 0; mr < 2; ++mr)
          o[mr][nc] = __builtin_amdgcn_mfma_f32_16x16x32_bf16(pa[mr][kk], vf, o[mr][nc], 0, 0, 0);
      }
    }
  }

  // epilogue: O/l -> [n][s][h*64+d] bf16 (ws, feeds k_proj_out)
  const int n = nh >> 3, h = nh & 7;
#pragma unroll
  for (int mr = 0; mr < 2; ++mr)
#pragma unroll
    for (int nc = 0; nc < 4; ++nc)
#pragma unroll
      for (int j = 0; j < 4; ++j) {
        int qrow = q0 + mr * 16 + hi16 * 4 + j;
        int e = h * 64 + nc * 16 + lo16;
        Og[((size_t)(n * SEQ + qrow)) * EMB + e] = f2bf(o[mr][nc][j] / lrow[mr][j]);
      }
}

extern "C" void kernel_launch(void* const* d_in, const int* in_sizes, int n_in,
                              void* d_out, int out_size, void* d_ws, size_t ws_size,
                              hipStream_t stream) {
  const float* xv  = (const float*)d_in[0];
  const float* xq  = (const float*)d_in[1];
  const float* xk  = (const float*)d_in[2];
  const float* wq  = (const float*)d_in[3];
  const float* wk  = (const float*)d_in[4];
  const float* wv  = (const float*)d_in[5];
  const float* wfc = (const float*)d_in[6];
  float* out = (float*)d_out;
  u16* ws    = (u16*)d_ws;

  const size_t PSZ = (size_t)NBATCH * HEADS * SEQ * HDIM;  // 4,194,304 elems
  if (ws_size < 4 * PSZ * sizeof(u16)) return;             // need 32 MiB scratch
  u16* qws = ws;
  u16* kws = ws + PSZ;
  u16* vws = ws + 2 * PSZ;
  u16* aws = ws + 3 * PSZ;

  k_proj_qkv<<<dim3(64, 4, 3), 256, 0, stream>>>(xq, xk, xv, wq, wk, wv, qws, kws, vws);
  k_attn<<<dim3(32, 16), 256, 0, stream>>>(qws, kws, vws, aws);
  k_proj_out<<<dim3(64, 4), 256, 0, stream>>>(aws, wfc, out);
}

// Round 4
// 226.404 us; speedup vs baseline: 1.3199x; 1.3199x over previous
//
#include <hip/hip_runtime.h>
#include <hip/hip_bf16.h>
#include <stdint.h>

typedef unsigned short u16;
typedef unsigned int u32;
typedef __attribute__((ext_vector_type(8))) short bf16x8;
typedef __attribute__((ext_vector_type(4))) float f32x4;
typedef __attribute__((ext_vector_type(16))) float f32x16;
typedef __attribute__((ext_vector_type(4))) u32 u32x4;

#define SEQ    4096
#define EMB    512
#define HEADS  8
#define HDIM   64
#define NBATCH 2

__device__ __forceinline__ u16 f2bf(float f) {
  unsigned u = __builtin_bit_cast(unsigned, f);
  u += 0x7fffu + ((u >> 16) & 1u);
  return (u16)(u >> 16);
}

__device__ __forceinline__ void gld_lds16(const void* g, void* lds) {
  __builtin_amdgcn_global_load_lds(
      (const __attribute__((address_space(1))) unsigned int*)(uintptr_t)g,
      (__attribute__((address_space(3))) unsigned int*)(uint32_t)(uintptr_t)lds,
      16, 0, 0);
}

#define CVT_PK(lo, hi) ({ u32 _r; \
  asm("v_cvt_pk_bf16_f32 %0, %1, %2" : "=v"(_r) : "v"(lo), "v"(hi)); _r; })

// Build one PV B-frag quad from 8 softmax'd scores (C-layout kv order).
// S[b+0..7] hold kv {0,1,2,3,8,9,10,11} (+4h, +16*(b/8) base). Result word w
// must hold k_local = h*8 + {2w, 2w+1}.
#define PACK_QUAD(dst, S, b) do { \
  u32 w0 = CVT_PK(S[b + 0], S[b + 1]); \
  u32 w1 = CVT_PK(S[b + 2], S[b + 3]); \
  u32 w2 = CVT_PK(S[b + 4], S[b + 5]); \
  u32 w3 = CVT_PK(S[b + 6], S[b + 7]); \
  u32 x0 = __shfl_xor(w0, 32), x1 = __shfl_xor(w1, 32); \
  u32 x2 = __shfl_xor(w2, 32), x3 = __shfl_xor(w3, 32); \
  dst = h ? (u32x4){x2, x3, w2, w3} : (u32x4){w0, w1, x0, x1}; \
} while (0)

// ---- shared 128x128 GEMM mainloop: C = X[m0:,512] * W[n0:,512]^T ----
template <bool XBF16>
__device__ __forceinline__ void gemm512_tile(const void* __restrict__ Xv,
                                             const float* __restrict__ W,
                                             u16* lA, u16* lB,
                                             int m0, int n0,
                                             f32x4 acc[4][4]) {
  const int tid  = threadIdx.x;
  const int lane = tid & 63;
  const int wid  = tid >> 6;
  const int wr   = wid >> 1, wc = wid & 1;

  for (int k0 = 0; k0 < EMB; k0 += 32) {
    __syncthreads();
    if constexpr (XBF16) {
      const u16* X = (const u16*)Xv;
      const int srow = lane >> 2;
      const int soff = (lane & 3) * 8;
#pragma unroll
      for (int i = 0; i < 2; ++i) {
        int rbase = wid * 32 + i * 16;
        gld_lds16(X + (size_t)(m0 + rbase + srow) * EMB + k0 + soff, lA + rbase * 32);
      }
    } else {
      const float* X = (const float*)Xv;
#pragma unroll
      for (int i = 0; i < 4; ++i) {
        int chunk = i * 256 + tid;
        int row = chunk >> 3;
        int c4  = (chunk & 7) * 4;
        float4 v = *(const float4*)(X + (size_t)(m0 + row) * EMB + k0 + c4);
        ushort4 b;
        b.x = f2bf(v.x); b.y = f2bf(v.y); b.z = f2bf(v.z); b.w = f2bf(v.w);
        *(ushort4*)(lA + row * 32 + c4) = b;
      }
    }
#pragma unroll
    for (int i = 0; i < 4; ++i) {
      int chunk = i * 256 + tid;
      int row = chunk >> 3;
      int c4  = (chunk & 7) * 4;
      float4 v = *(const float4*)(W + (size_t)(n0 + row) * EMB + k0 + c4);
      ushort4 b;
      b.x = f2bf(v.x); b.y = f2bf(v.y); b.z = f2bf(v.z); b.w = f2bf(v.w);
      *(ushort4*)(lB + row * 32 + c4) = b;
    }
    __syncthreads();

    bf16x8 a[4], b[4];
#pragma unroll
    for (int t = 0; t < 4; ++t) {
      a[t] = *(const bf16x8*)(lA + (wr * 64 + t * 16 + (lane & 15)) * 32 + (lane >> 4) * 8);
      b[t] = *(const bf16x8*)(lB + (wc * 64 + t * 16 + (lane & 15)) * 32 + (lane >> 4) * 8);
    }
#pragma unroll
    for (int mr = 0; mr < 4; ++mr)
#pragma unroll
      for (int nc = 0; nc < 4; ++nc)
        acc[mr][nc] = __builtin_amdgcn_mfma_f32_16x16x32_bf16(a[mr], b[nc], acc[mr][nc], 0, 0, 0);
  }
}

__global__ __launch_bounds__(256, 2) void k_proj_qkv(
    const float* __restrict__ xq, const float* __restrict__ xk, const float* __restrict__ xv,
    const float* __restrict__ wq, const float* __restrict__ wk, const float* __restrict__ wv,
    u16* __restrict__ yq, u16* __restrict__ yk, u16* __restrict__ yv) {
  __shared__ u16 lA[128 * 32];
  __shared__ u16 lB[128 * 32];
  const int z = blockIdx.z;
  const float* X = (z == 0) ? xq : (z == 1) ? xk : xv;
  const float* W = (z == 0) ? wq : (z == 1) ? wk : wv;
  u16* Y         = (z == 0) ? yq : (z == 1) ? yk : yv;
  const float oscale = (z == 0) ? 0.04419417382f : 1.0f;  // 1/sqrt(512) into Q
  const int m0 = blockIdx.x * 128, n0 = blockIdx.y * 128;

  f32x4 acc[4][4] = {};
  gemm512_tile<false>(X, W, lA, lB, m0, n0, acc);

  const int lane = threadIdx.x & 63, wid = threadIdx.x >> 6;
  const int wr = wid >> 1, wc = wid & 1;
#pragma unroll
  for (int mr = 0; mr < 4; ++mr)
#pragma unroll
    for (int nc = 0; nc < 4; ++nc)
#pragma unroll
      for (int j = 0; j < 4; ++j) {
        int m = m0 + wr * 64 + mr * 16 + (lane >> 4) * 4 + j;
        int c = n0 + wc * 64 + nc * 16 + (lane & 15);
        int n = m >> 12, s = m & (SEQ - 1);
        int h = c >> 6, d = c & 63;
        Y[(((size_t)(n * HEADS + h)) * SEQ + s) * HDIM + d] = f2bf(acc[mr][nc][j] * oscale);
      }
}

__global__ __launch_bounds__(256, 2) void k_proj_out(
    const u16* __restrict__ X, const float* __restrict__ W, float* __restrict__ Y) {
  __shared__ u16 lA[128 * 32];
  __shared__ u16 lB[128 * 32];
  const int m0 = blockIdx.x * 128, n0 = blockIdx.y * 128;
  f32x4 acc[4][4] = {};
  gemm512_tile<true>(X, W, lA, lB, m0, n0, acc);

  const int lane = threadIdx.x & 63, wid = threadIdx.x >> 6;
  const int wr = wid >> 1, wc = wid & 1;
#pragma unroll
  for (int mr = 0; mr < 4; ++mr)
#pragma unroll
    for (int nc = 0; nc < 4; ++nc)
#pragma unroll
      for (int j = 0; j < 4; ++j) {
        int m = m0 + wr * 64 + mr * 16 + (lane >> 4) * 4 + j;
        int c = n0 + wc * 64 + nc * 16 + (lane & 15);
        Y[(size_t)m * EMB + c] = acc[mr][nc][j];
      }
}

// ---- flash attention, swapped-operand 32x32 structure ----
// grid (32,16); 4 waves x 32 q-rows; KVBLK=64; dbuf K/V; softmax in-register.
__global__ __launch_bounds__(256, 2) void k_attn(
    const u16* __restrict__ Qg, const u16* __restrict__ Kg,
    const u16* __restrict__ Vg, u16* __restrict__ Og) {
  __shared__ u16 lK[2][64 * 64];   // [kv][d], granule col ^ ((kv&7)<<3)
  __shared__ u16 lV[2][64 * 64];   // [d][kv], kv ^ ((((d>>3)^d)&7)<<3)

  const int tid = threadIdx.x, lane = tid & 63, wid = tid >> 6;
  const int l31 = lane & 31, h = lane >> 5;
  const int nh = blockIdx.y;
  const int q0 = blockIdx.x * 128 + wid * 32;

  const u16* Qh = Qg + (size_t)nh * SEQ * HDIM;
  const u16* Kh = Kg + (size_t)nh * SEQ * HDIM;
  const u16* Vh = Vg + (size_t)nh * SEQ * HDIM;

  // Q B-frags: q = q0+l31, k(d) = t*16 + h*8 + j   (Q pre-scaled by 1/sqrt(512))
  bf16x8 qf[4];
#pragma unroll
  for (int t = 0; t < 4; ++t)
    qf[t] = *(const bf16x8*)&Qh[(size_t)(q0 + l31) * HDIM + t * 16 + h * 8];

  f32x16 o0 = {}, o1 = {};          // O^T tiles: d 0-31 / 32-63 (rows), q = lane
  float m = -1e30f, lsum = 0.f;

  const int kvr = tid >> 3, cb = (tid & 7) * 8;   // V staging coords

  // ---- prologue: stage tile 0 ----
#pragma unroll
  for (int i = 0; i < 2; ++i) {
    int g = (wid * 2 + i) * 64 + lane;
    int kr = g >> 3, kc = g & 7;
    gld_lds16(Kh + (size_t)kr * HDIM + ((kc * 8) ^ ((kr & 7) << 3)),
              &lK[0][(wid * 2 + i) * 512]);
  }
  {
    bf16x8 va = *(const bf16x8*)&Vh[(size_t)kvr * HDIM + cb];
    bf16x8 vb = *(const bf16x8*)&Vh[(size_t)(kvr + 32) * HDIM + cb];
#pragma unroll
    for (int j = 0; j < 8; ++j) {
      int d = cb + j, sw = (((d >> 3) ^ d) & 7) << 3;
      lV[0][d * 64 + (kvr ^ sw)] = (u16)va[j];
      lV[0][d * 64 + ((kvr + 32) ^ sw)] = (u16)vb[j];
    }
  }
  asm volatile("s_waitcnt vmcnt(0)" ::: "memory");
  __syncthreads();

  for (int t = 0; t < SEQ / 64; ++t) {
    const int cur = t & 1, nxt = cur ^ 1;
    const int kv0 = t * 64;

    // issue next-tile staging early (T14)
    bf16x8 va, vb;
    if (t < SEQ / 64 - 1) {
      const u16* Kn = Kh + (size_t)(kv0 + 64) * HDIM;
#pragma unroll
      for (int i = 0; i < 2; ++i) {
        int g = (wid * 2 + i) * 64 + lane;
        int kr = g >> 3, kc = g & 7;
        gld_lds16(Kn + (size_t)kr * HDIM + ((kc * 8) ^ ((kr & 7) << 3)),
                  &lK[nxt][(wid * 2 + i) * 512]);
      }
      const u16* Vn = Vh + (size_t)(kv0 + 64) * HDIM;
      va = *(const bf16x8*)&Vn[(size_t)kvr * HDIM + cb];
      vb = *(const bf16x8*)&Vn[(size_t)(kvr + 32) * HDIM + cb];
    }

    // ---- QK^T (swapped): S^T = K * Q^T ; sA = kv 0-31, sB = kv 32-63 ----
    f32x16 sA = {}, sB = {};
    __builtin_amdgcn_s_setprio(1);
#pragma unroll
    for (int tt = 0; tt < 4; ++tt) {
      int co = (tt * 16 + h * 8) ^ ((l31 & 7) << 3);
      bf16x8 k0 = *(const bf16x8*)&lK[cur][l31 * 64 + co];
      bf16x8 k1 = *(const bf16x8*)&lK[cur][(32 + l31) * 64 + co];
      sA = __builtin_amdgcn_mfma_f32_32x32x16_bf16(k0, qf[tt], sA, 0, 0, 0);
      sB = __builtin_amdgcn_mfma_f32_32x32x16_bf16(k1, qf[tt], sB, 0, 0, 0);
    }
    __builtin_amdgcn_s_setprio(0);

    // ---- exact online softmax, in-register (lane pair owns q = q0+l31) ----
    float mx = fmaxf(sA[0], sB[0]);
#pragma unroll
    for (int r = 1; r < 16; ++r) mx = fmaxf(mx, fmaxf(sA[r], sB[r]));
    mx = fmaxf(mx, __shfl_xor(mx, 32));

    float mn = fmaxf(m, mx);
    float al = __expf(m - mn);
    m = mn;
    lsum *= al;
#pragma unroll
    for (int r = 0; r < 16; ++r) { o0[r] *= al; o1[r] *= al; }

    const float L2E = 1.44269504f;
    float mc = mn * L2E;
    float ps = 0.f;
#pragma unroll
    for (int r = 0; r < 16; ++r) {
      sA[r] = exp2f(fmaf(sA[r], L2E, -mc));
      sB[r] = exp2f(fmaf(sB[r], L2E, -mc));
      ps += sA[r] + sB[r];
    }
    ps += __shfl_xor(ps, 32);
    lsum += ps;

    // ---- pack P -> PV B-frags in registers (shfl_xor cross-half) ----
    u32x4 pfr[4];
    PACK_QUAD(pfr[0], sA, 0);
    PACK_QUAD(pfr[1], sA, 8);
    PACK_QUAD(pfr[2], sB, 0);
    PACK_QUAD(pfr[3], sB, 8);

    // ---- PV: O^T = V^T * P^T ----
#pragma unroll
    for (int dt = 0; dt < 2; ++dt) {
      bf16x8 vf[4];
#pragma unroll
      for (int tt = 0; tt < 4; ++tt) {
        int d = dt * 32 + l31;
        int sw = (((d >> 3) ^ d) & 7) << 3;
        vf[tt] = *(const bf16x8*)&lV[cur][d * 64 + ((tt * 16 + h * 8) ^ sw)];
      }
      __builtin_amdgcn_s_setprio(1);
#pragma unroll
      for (int tt = 0; tt < 4; ++tt) {
        bf16x8 pb = __builtin_bit_cast(bf16x8, pfr[tt]);
        if (dt == 0) o0 = __builtin_amdgcn_mfma_f32_32x32x16_bf16(vf[tt], pb, o0, 0, 0, 0);
        else         o1 = __builtin_amdgcn_mfma_f32_32x32x16_bf16(vf[tt], pb, o1, 0, 0, 0);
      }
      __builtin_amdgcn_s_setprio(0);
    }

    // ---- late V write (loads hidden under compute), drain, barrier ----
    if (t < SEQ / 64 - 1) {
#pragma unroll
      for (int j = 0; j < 8; ++j) {
        int d = cb + j, sw = (((d >> 3) ^ d) & 7) << 3;
        lV[nxt][d * 64 + (kvr ^ sw)] = (u16)va[j];
        lV[nxt][d * 64 + ((kvr + 32) ^ sw)] = (u16)vb[j];
      }
    }
    asm volatile("s_waitcnt vmcnt(0)" ::: "memory");
    __syncthreads();
  }

  // ---- epilogue: O^T/l -> [n][s][h*64+d] bf16 ----
  const float linv = 1.f / lsum;
  const int n = nh >> 3, hh = nh & 7;
  const int q = q0 + l31;
#pragma unroll
  for (int r = 0; r < 16; ++r) {
    int row = (r & 3) + 8 * (r >> 2) + 4 * h;
    Og[((size_t)(n * SEQ + q)) * EMB + hh * 64 + row] = f2bf(o0[r] * linv);
    Og[((size_t)(n * SEQ + q)) * EMB + hh * 64 + 32 + row] = f2bf(o1[r] * linv);
  }
}

extern "C" void kernel_launch(void* const* d_in, const int* in_sizes, int n_in,
                              void* d_out, int out_size, void* d_ws, size_t ws_size,
                              hipStream_t stream) {
  const float* xv  = (const float*)d_in[0];
  const float* xq  = (const float*)d_in[1];
  const float* xk  = (const float*)d_in[2];
  const float* wq  = (const float*)d_in[3];
  const float* wk  = (const float*)d_in[4];
  const float* wv  = (const float*)d_in[5];
  const float* wfc = (const float*)d_in[6];
  float* out = (float*)d_out;
  u16* ws    = (u16*)d_ws;

  const size_t PSZ = (size_t)NBATCH * HEADS * SEQ * HDIM;  // 4,194,304 elems
  if (ws_size < 4 * PSZ * sizeof(u16)) return;             // need 32 MiB scratch
  u16* qws = ws;
  u16* kws = ws + PSZ;
  u16* vws = ws + 2 * PSZ;
  u16* aws = ws + 3 * PSZ;

  k_proj_qkv<<<dim3(64, 4, 3), 256, 0, stream>>>(xq, xk, xv, wq, wk, wv, qws, kws, vws);
  k_attn<<<dim3(32, 16), 256, 0, stream>>>(qws, kws, vws, aws);
  k_proj_out<<<dim3(64, 4), 256, 0, stream>>>(aws, wfc, out);
}